// Round 1
// baseline (2235.935 us; speedup 1.0000x reference)
//
#include <hip/hip_runtime.h>
#include <cstdint>
#include <cstddef>

typedef unsigned short u16;
typedef float f32x4 __attribute__((ext_vector_type(4)));
typedef short s16x8 __attribute__((ext_vector_type(8)));
typedef unsigned short u16x4 __attribute__((ext_vector_type(4)));

#define DEV static __device__ __forceinline__

DEV u16 f2bf(float f) {
  uint32_t x = __float_as_uint(f);
  return (u16)((x + 0x7fffu + ((x >> 16) & 1u)) >> 16);  // RNE
}
DEV float bf2f(u16 u) { return __uint_as_float(((uint32_t)u) << 16); }

DEV int swz(int b) { return b ^ ((b >> 2) & 0x70); }  // XOR bank swizzle within 512B stripe

DEV void mfma_bf16(f32x4& acc, s16x8 a, s16x8 b) {
  asm volatile("v_mfma_f32_16x16x32_bf16 %0, %1, %2, %0" : "+v"(acc) : "v"(a), "v"(b));
}

// ---------------- copy x_cls -> d_out (fp32 passthrough base) ----------------
__global__ __launch_bounds__(256) void k_copy(const float* __restrict__ src,
                                              float* __restrict__ dst, int n4) {
  int i = blockIdx.x * blockDim.x + threadIdx.x;
  const float4* s = (const float4*)src;
  float4* d = (float4*)dst;
  for (; i < n4; i += gridDim.x * blockDim.x) d[i] = s[i];
}

// ---------------- fp32 -> bf16 cast (weight packing; weights are [N][K] row-major already) ---
__global__ __launch_bounds__(256) void k_cast4(const float* __restrict__ src,
                                               u16* __restrict__ dst, int n4) {
  int i = blockIdx.x * blockDim.x + threadIdx.x;
  for (; i < n4; i += gridDim.x * blockDim.x) {
    float4 v = ((const float4*)src)[i];
    u16x4 o;
    o[0] = f2bf(v.x); o[1] = f2bf(v.y); o[2] = f2bf(v.z); o[3] = f2bf(v.w);
    ((u16x4*)dst)[i] = o;
  }
}

// ---------------- LayerNorm (wave per token, 256 ch, lane holds float4) ----------------
// mode 0: ln2 over cls tokens (ntok=4800), src = xc rows
// mode 1: ln1 over concat(u) tokens (ntok=134400), src = xc(cls part) / x_patch; dup cls rows
__global__ __launch_bounds__(256) void k_ln(const float* __restrict__ xc,
                                            const float* __restrict__ xpatch,
                                            const float* __restrict__ lw,
                                            const float* __restrict__ lb,
                                            u16* __restrict__ out_full,
                                            u16* __restrict__ out_cls,
                                            int mode, int ntok) {
  int wave = threadIdx.x >> 6, lane = threadIdx.x & 63;
  int tok = blockIdx.x * 4 + wave;
  if (tok >= ntok) return;
  const float* row;
  int b = 0, t = 0;
  if (mode == 1) {
    b = tok / 2100;
    t = tok - b * 2100;
    row = (t < 75) ? (xc + (size_t)(b * 75 + t) * 256)
                   : (xpatch + (size_t)(b * 2025 + (t - 75)) * 256);
  } else {
    row = xc + (size_t)tok * 256;
  }
  float4 v = ((const float4*)row)[lane];
  float s = v.x + v.y + v.z + v.w;
  float q = v.x * v.x + v.y * v.y + v.z * v.z + v.w * v.w;
#pragma unroll
  for (int m = 1; m < 64; m <<= 1) {
    s += __shfl_xor(s, m, 64);
    q += __shfl_xor(q, m, 64);
  }
  float mean = s * (1.f / 256.f);
  float var = q * (1.f / 256.f) - mean * mean;
  float rstd = rsqrtf(var + 1e-5f);
  float4 w4 = ((const float4*)lw)[lane];
  float4 b4 = ((const float4*)lb)[lane];
  u16x4 o;
  o[0] = f2bf((v.x - mean) * rstd * w4.x + b4.x);
  o[1] = f2bf((v.y - mean) * rstd * w4.y + b4.y);
  o[2] = f2bf((v.z - mean) * rstd * w4.z + b4.z);
  o[3] = f2bf((v.w - mean) * rstd * w4.w + b4.w);
  ((u16x4*)(out_full + (size_t)tok * 256))[lane] = o;
  if (mode == 1 && t < 75)
    ((u16x4*)(out_cls + (size_t)(b * 75 + t) * 256))[lane] = o;
}

// ---------------- Generic bf16 MFMA GEMM: C[M,N] = A[M,K] @ Bw[N,K]^T ----------------
// modes: 0 = store bf16 (kv); 1 = store fp32 * scale (q); 2 = of32 += gamma*(v+bias) (proj/fc2);
//        3 = store bf16 gelu(v+bias) (fc1)
__global__ __launch_bounds__(256) void k_gemm(const u16* __restrict__ A,
                                              const u16* __restrict__ Bw,
                                              int M, int N, int K, int mode, float scale,
                                              const float* __restrict__ bias,
                                              const float* __restrict__ gamma,
                                              u16* __restrict__ obf,
                                              float* __restrict__ of32) {
  __shared__ __align__(16) char smA[8192];
  __shared__ __align__(16) char smB[8192];
  const int tid = threadIdx.x;
  const int lane = tid & 63, wid = tid >> 6;
  const int wm = wid >> 1, wn = wid & 1;
  const int m0 = blockIdx.x * 128, n0 = blockIdx.y * 128;
  const int g = lane >> 4, l15 = lane & 15;

  f32x4 acc[4][4] = {};

  for (int k0 = 0; k0 < K; k0 += 32) {
#pragma unroll
    for (int c = 0; c < 2; c++) {
      int e = tid + c * 256;
      int row = e >> 2, seg = e & 3;
      int am = m0 + row;
      if (am > M - 1) am = M - 1;
      s16x8 av = *(const s16x8*)(A + (size_t)am * K + k0 + seg * 8);
      *(s16x8*)(smA + swz(e * 16)) = av;
      s16x8 bv = *(const s16x8*)(Bw + (size_t)(n0 + row) * K + k0 + seg * 8);
      *(s16x8*)(smB + swz(e * 16)) = bv;
    }
    __syncthreads();
    s16x8 af[4], bfr[4];
#pragma unroll
    for (int i = 0; i < 4; i++) {
      int lm = wm * 64 + i * 16 + l15;
      af[i] = *(const s16x8*)(smA + swz(lm * 64 + g * 16));
      int ln = wn * 64 + i * 16 + l15;
      bfr[i] = *(const s16x8*)(smB + swz(ln * 64 + g * 16));
    }
#pragma unroll
    for (int i = 0; i < 4; i++)
#pragma unroll
      for (int j = 0; j < 4; j++) mfma_bf16(acc[i][j], af[i], bfr[j]);
    __syncthreads();
  }
  asm volatile("s_nop 7\n\ts_nop 7" ::: "memory");  // MFMA -> VALU hazard guard

#pragma unroll
  for (int i = 0; i < 4; i++) {
#pragma unroll
    for (int j = 0; j < 4; j++) {
      int gmBase = m0 + wm * 64 + i * 16 + g * 4;
      int gn = n0 + wn * 64 + j * 16 + l15;
#pragma unroll
      for (int r = 0; r < 4; r++) {
        int gm = gmBase + r;
        if (gm >= M) continue;
        float v = acc[i][j][r];
        if (mode == 0) {
          obf[(size_t)gm * N + gn] = f2bf(v);
        } else if (mode == 1) {
          of32[(size_t)gm * N + gn] = v * scale;
        } else if (mode == 2) {
          of32[(size_t)gm * N + gn] += gamma[gn] * (v + bias[gn]);
        } else {  // 3: gelu exact
          float x = v + bias[gn];
          obf[(size_t)gm * N + gn] = f2bf(0.5f * x * (1.f + erff(x * 0.70710678118654752f)));
        }
      }
    }
  }
}

// ---------------- Attention: one block per (b,h); VALU flash w/ online softmax ----------------
// kv layout: [b*2100+n][512] bf16, cols 0..255 = K proj, 256..511 = V proj; head h at h*32.
__global__ __launch_bounds__(256) void k_attn(const float* __restrict__ qbuf,
                                              const u16* __restrict__ kv,
                                              u16* __restrict__ obf) {
  __shared__ __align__(16) float qs[2400];   // 75 x 32
  __shared__ float accs[2400];               // 75 x 32
  __shared__ float vt[2048];                 // 64 x 32
  __shared__ float mrow[75], lrow[75];
  int bid = blockIdx.x;
  int b = bid & 63, h = bid >> 6;  // low bits = batch -> all 8 heads of b on same XCD (L2 reuse)
  int tid = threadIdx.x, lane = tid & 63, wave = tid >> 6;
  size_t kvbase = (size_t)b * 2100 * 512;

  for (int idx = tid; idx < 2400; idx += 256) {
    int r = idx >> 5, d = idx & 31;
    qs[idx] = qbuf[(size_t)(b * 75 + r) * 256 + h * 32 + d];
    accs[idx] = 0.f;
  }
  for (int idx = tid; idx < 75; idx += 256) { mrow[idx] = -1e30f; lrow[idx] = 0.f; }
  __syncthreads();

  int half = lane >> 5, dl = lane & 31;
  for (int t0 = 0; t0 < 2100; t0 += 64) {
    // stage V tile (fp32, [64][32] row-aligned -> conflict-free col reads)
    for (int idx = tid; idx < 2048; idx += 256) {
      int tt = idx >> 5, d = idx & 31;
      int n = t0 + tt;
      vt[idx] = (n < 2100) ? bf2f(kv[kvbase + (size_t)n * 512 + 256 + h * 32 + d]) : 0.f;
    }
    // K row of this lane's token -> registers
    int n = t0 + lane;
    int nld = n < 2100 ? n : 2099;
    bool tokvalid = n < 2100;
    float kreg[32];
    const u16* kp = kv + kvbase + (size_t)nld * 512 + h * 32;
#pragma unroll
    for (int sg = 0; sg < 4; sg++) {
      s16x8 kw = *(const s16x8*)(kp + sg * 8);
#pragma unroll
      for (int e = 0; e < 8; e++) kreg[sg * 8 + e] = bf2f((u16)kw[e]);
    }
    __syncthreads();
    // V column (this lane's d, its half's 32 tokens) -> registers
    float vreg[32];
#pragma unroll
    for (int n2 = 0; n2 < 32; n2++) vreg[n2] = vt[(half * 32 + n2) * 32 + dl];

    for (int j = 0; j < 19; ++j) {
      int r = wave + 4 * j;
      if (r >= 75) break;
      // phase 1: logits, lane = token
      float s = -1e30f;
      if (tokvalid) {
        s = 0.f;
        const float4* q4 = (const float4*)(qs + r * 32);
#pragma unroll
        for (int jj = 0; jj < 8; jj++) {
          float4 qv = q4[jj];
          s += qv.x * kreg[4 * jj] + qv.y * kreg[4 * jj + 1] +
               qv.z * kreg[4 * jj + 2] + qv.w * kreg[4 * jj + 3];
        }
      }
      float smax = s;
#pragma unroll
      for (int m = 1; m < 64; m <<= 1) smax = fmaxf(smax, __shfl_xor(smax, m, 64));
      float mold = mrow[r];
      float mnew = fmaxf(mold, smax);
      float rescale = __expf(mold - mnew);
      float p = __expf(s - mnew);
      float psum = p;
#pragma unroll
      for (int m = 1; m < 64; m <<= 1) psum += __shfl_xor(psum, m, 64);
      if (lane == 0) {
        mrow[r] = mnew;
        lrow[r] = lrow[r] * rescale + psum;
      }
      // phase 2: PV, lane = (half, d); gather p via shuffle
      float partial = 0.f;
#pragma unroll
      for (int n2 = 0; n2 < 32; n2++) {
        float pv = __shfl(p, half * 32 + n2, 64);
        partial += pv * vreg[n2];
      }
      partial += __shfl_xor(partial, 32, 64);
      if (lane < 32) {
        int ai = r * 32 + dl;
        accs[ai] = accs[ai] * rescale + partial;
      }
    }
    __syncthreads();
  }
  for (int idx = tid; idx < 2400; idx += 256) {
    int r = idx >> 5, d = idx & 31;
    obf[(size_t)(b * 75 + r) * 256 + h * 32 + d] = f2bf(accs[idx] / lrow[r]);
  }
}

// ---------------- host ----------------
extern "C" void kernel_launch(void* const* d_in, const int* in_sizes, int n_in,
                              void* d_out, int out_size, void* d_ws, size_t ws_size,
                              hipStream_t stream) {
  const float* x_cls   = (const float*)d_in[0];
  const float* x_patch = (const float*)d_in[1];
  const float* ln1_w   = (const float*)d_in[2];
  const float* ln1_b   = (const float*)d_in[3];
  const float* q_w     = (const float*)d_in[4];
  const float* k_w     = (const float*)d_in[5];
  const float* v_w     = (const float*)d_in[6];
  const float* proj_w  = (const float*)d_in[7];
  const float* proj_b  = (const float*)d_in[8];
  const float* ln2_w   = (const float*)d_in[9];
  const float* ln2_b   = (const float*)d_in[10];
  const float* fc1_w   = (const float*)d_in[11];
  const float* fc1_b   = (const float*)d_in[12];
  const float* fc2_w   = (const float*)d_in[13];
  const float* fc2_b   = (const float*)d_in[14];
  const float* gamma1  = (const float*)d_in[15];
  const float* gamma2  = (const float*)d_in[16];
  float* xc = (float*)d_out;

  char* ws = (char*)d_ws;
  size_t off = 0;
  auto alloc = [&](size_t bytes) {
    char* p = ws + off;
    off += (bytes + 255) & ~(size_t)255;
    return p;
  };
  u16* un    = (u16*)alloc(134400ull * 256 * 2);
  u16* uncls = (u16*)alloc(4800ull * 256 * 2);
  u16* kvb   = (u16*)alloc(134400ull * 512 * 2);
  float* qb  = (float*)alloc(4800ull * 256 * 4);
  u16* ob    = (u16*)alloc(4800ull * 256 * 2);
  u16* xn    = (u16*)alloc(4800ull * 256 * 2);
  u16* hb    = (u16*)alloc(4800ull * 1024 * 2);
  u16* qp    = (u16*)alloc(2ull * 65536 * 2);
  u16* kvp   = (u16*)alloc(2ull * 131072 * 2);
  u16* pjp   = (u16*)alloc(2ull * 65536 * 2);
  u16* f1p   = (u16*)alloc(2ull * 262144 * 2);
  u16* f2p   = (u16*)alloc(2ull * 262144 * 2);

  k_copy<<<1200, 256, 0, stream>>>(x_cls, xc, 307200);
  for (int i = 0; i < 2; i++) {
    k_cast4<<<64, 256, 0, stream>>>(q_w + i * 65536, qp + i * 65536, 16384);
    k_cast4<<<64, 256, 0, stream>>>(k_w + i * 65536, kvp + i * 131072, 16384);
    k_cast4<<<64, 256, 0, stream>>>(v_w + i * 65536, kvp + i * 131072 + 65536, 16384);
    k_cast4<<<64, 256, 0, stream>>>(proj_w + i * 65536, pjp + i * 65536, 16384);
    k_cast4<<<256, 256, 0, stream>>>(fc1_w + i * 262144, f1p + i * 262144, 65536);
    k_cast4<<<256, 256, 0, stream>>>(fc2_w + i * 262144, f2p + i * 262144, 65536);
  }

  const float qscale = 0.17677669529663688f;
  for (int i = 0; i < 2; i++) {
    k_ln<<<33600, 256, 0, stream>>>(xc, x_patch, ln1_w + i * 256, ln1_b + i * 256,
                                    un, uncls, 1, 134400);
    dim3 gkv(1050, 4);
    k_gemm<<<gkv, 256, 0, stream>>>(un, kvp + i * 131072, 134400, 512, 256, 0, 0.f,
                                    nullptr, nullptr, kvb, nullptr);
    dim3 gq(38, 2);
    k_gemm<<<gq, 256, 0, stream>>>(uncls, qp + i * 65536, 4800, 256, 256, 1, qscale,
                                   nullptr, nullptr, nullptr, qb);
    k_attn<<<512, 256, 0, stream>>>(qb, kvb, ob);
    k_gemm<<<gq, 256, 0, stream>>>(ob, pjp + i * 65536, 4800, 256, 256, 2, 0.f,
                                   proj_b + i * 256, gamma1 + i * 256, nullptr, xc);
    k_ln<<<1200, 256, 0, stream>>>(xc, nullptr, ln2_w + i * 256, ln2_b + i * 256,
                                   xn, nullptr, 0, 4800);
    dim3 gf1(38, 8);
    k_gemm<<<gf1, 256, 0, stream>>>(xn, f1p + i * 262144, 4800, 1024, 256, 3, 0.f,
                                    fc1_b + i * 1024, nullptr, hb, nullptr);
    k_gemm<<<gq, 256, 0, stream>>>(hb, f2p + i * 262144, 4800, 256, 1024, 2, 0.f,
                                   fc2_b + i * 256, gamma2 + i * 256, nullptr, xc);
  }
}

// Round 2
// 616.528 us; speedup vs baseline: 3.6267x; 3.6267x over previous
//
#include <hip/hip_runtime.h>
#include <cstdint>
#include <cstddef>

typedef unsigned short u16;
typedef float f32x4 __attribute__((ext_vector_type(4)));
typedef short s16x8 __attribute__((ext_vector_type(8)));
typedef unsigned short u16x4 __attribute__((ext_vector_type(4)));
typedef __bf16 bf16x8 __attribute__((ext_vector_type(8)));

#define DEV static __device__ __forceinline__

DEV u16 f2bf(float f) {
  uint32_t x = __float_as_uint(f);
  return (u16)((x + 0x7fffu + ((x >> 16) & 1u)) >> 16);  // RNE
}
DEV float bf2f(u16 u) { return __uint_as_float(((uint32_t)u) << 16); }

DEV int swz(int b) { return b ^ ((b >> 2) & 0x70); }

DEV void mfma_bf16_asm(f32x4& acc, s16x8 a, s16x8 b) {
  asm volatile("v_mfma_f32_16x16x32_bf16 %0, %1, %2, %0" : "+v"(acc) : "v"(a), "v"(b));
}

DEV f32x4 mfma16(bf16x8 a, bf16x8 b, f32x4 c) {
  return __builtin_amdgcn_mfma_f32_16x16x32_bf16(a, b, c, 0, 0, 0);
}

DEV uint32_t pkbf(float lo, float hi) {
  uint32_t r;
  asm("v_cvt_pk_bf16_f32 %0, %1, %2" : "=v"(r) : "v"(lo), "v"(hi));
  return r;
}

// ---------------- copy x_cls -> d_out ----------------
__global__ __launch_bounds__(256) void k_copy(const float* __restrict__ src,
                                              float* __restrict__ dst, int n4) {
  int i = blockIdx.x * blockDim.x + threadIdx.x;
  const float4* s = (const float4*)src;
  float4* d = (float4*)dst;
  for (; i < n4; i += gridDim.x * blockDim.x) d[i] = s[i];
}

// ---------------- fp32 -> bf16 cast ----------------
__global__ __launch_bounds__(256) void k_cast4(const float* __restrict__ src,
                                               u16* __restrict__ dst, int n4) {
  int i = blockIdx.x * blockDim.x + threadIdx.x;
  for (; i < n4; i += gridDim.x * blockDim.x) {
    float4 v = ((const float4*)src)[i];
    u16x4 o;
    o[0] = f2bf(v.x); o[1] = f2bf(v.y); o[2] = f2bf(v.z); o[3] = f2bf(v.w);
    ((u16x4*)dst)[i] = o;
  }
}

// ---------------- LayerNorm ----------------
__global__ __launch_bounds__(256) void k_ln(const float* __restrict__ xc,
                                            const float* __restrict__ xpatch,
                                            const float* __restrict__ lw,
                                            const float* __restrict__ lb,
                                            u16* __restrict__ out_full,
                                            u16* __restrict__ out_cls,
                                            int mode, int ntok) {
  int wave = threadIdx.x >> 6, lane = threadIdx.x & 63;
  int tok = blockIdx.x * 4 + wave;
  if (tok >= ntok) return;
  const float* row;
  int b = 0, t = 0;
  if (mode == 1) {
    b = tok / 2100;
    t = tok - b * 2100;
    row = (t < 75) ? (xc + (size_t)(b * 75 + t) * 256)
                   : (xpatch + (size_t)(b * 2025 + (t - 75)) * 256);
  } else {
    row = xc + (size_t)tok * 256;
  }
  float4 v = ((const float4*)row)[lane];
  float s = v.x + v.y + v.z + v.w;
  float q = v.x * v.x + v.y * v.y + v.z * v.z + v.w * v.w;
#pragma unroll
  for (int m = 1; m < 64; m <<= 1) {
    s += __shfl_xor(s, m, 64);
    q += __shfl_xor(q, m, 64);
  }
  float mean = s * (1.f / 256.f);
  float var = q * (1.f / 256.f) - mean * mean;
  float rstd = rsqrtf(var + 1e-5f);
  float4 w4 = ((const float4*)lw)[lane];
  float4 b4 = ((const float4*)lb)[lane];
  u16x4 o;
  o[0] = f2bf((v.x - mean) * rstd * w4.x + b4.x);
  o[1] = f2bf((v.y - mean) * rstd * w4.y + b4.y);
  o[2] = f2bf((v.z - mean) * rstd * w4.z + b4.z);
  o[3] = f2bf((v.w - mean) * rstd * w4.w + b4.w);
  ((u16x4*)(out_full + (size_t)tok * 256))[lane] = o;
  if (mode == 1 && t < 75)
    ((u16x4*)(out_cls + (size_t)(b * 75 + t) * 256))[lane] = o;
}

// ---------------- Generic bf16 MFMA GEMM: C[M,N] = A[M,K] @ Bw[N,K]^T ----------------
// modes: 0 = kv plane store bf16: out[(n>>5)*M + m][32] (planes 0..7 K-heads, 8..15 V-heads)
//        1 = store bf16 (v*scale) row-major   (q, pre-scaled for exp2 softmax)
//        2 = of32 += gamma*(v+bias)           (proj/fc2 residual)
//        3 = store bf16 gelu(v+bias)          (fc1)
__global__ __launch_bounds__(256) void k_gemm(const u16* __restrict__ A,
                                              const u16* __restrict__ Bw,
                                              int M, int N, int K, int mode, float scale,
                                              const float* __restrict__ bias,
                                              const float* __restrict__ gamma,
                                              u16* __restrict__ obf,
                                              float* __restrict__ of32) {
  __shared__ __align__(16) char smA[8192];
  __shared__ __align__(16) char smB[8192];
  const int tid = threadIdx.x;
  const int lane = tid & 63, wid = tid >> 6;
  const int wm = wid >> 1, wn = wid & 1;
  const int m0 = blockIdx.x * 128, n0 = blockIdx.y * 128;
  const int g = lane >> 4, l15 = lane & 15;

  f32x4 acc[4][4] = {};

  for (int k0 = 0; k0 < K; k0 += 32) {
#pragma unroll
    for (int c = 0; c < 2; c++) {
      int e = tid + c * 256;
      int row = e >> 2, seg = e & 3;
      int am = m0 + row;
      if (am > M - 1) am = M - 1;
      s16x8 av = *(const s16x8*)(A + (size_t)am * K + k0 + seg * 8);
      *(s16x8*)(smA + swz(e * 16)) = av;
      s16x8 bv = *(const s16x8*)(Bw + (size_t)(n0 + row) * K + k0 + seg * 8);
      *(s16x8*)(smB + swz(e * 16)) = bv;
    }
    __syncthreads();
    s16x8 af[4], bfr[4];
#pragma unroll
    for (int i = 0; i < 4; i++) {
      int lm = wm * 64 + i * 16 + l15;
      af[i] = *(const s16x8*)(smA + swz(lm * 64 + g * 16));
      int ln = wn * 64 + i * 16 + l15;
      bfr[i] = *(const s16x8*)(smB + swz(ln * 64 + g * 16));
    }
#pragma unroll
    for (int i = 0; i < 4; i++)
#pragma unroll
      for (int j = 0; j < 4; j++) mfma_bf16_asm(acc[i][j], af[i], bfr[j]);
    __syncthreads();
  }
  asm volatile("s_nop 7\n\ts_nop 7" ::: "memory");

#pragma unroll
  for (int i = 0; i < 4; i++) {
#pragma unroll
    for (int j = 0; j < 4; j++) {
      int gmBase = m0 + wm * 64 + i * 16 + g * 4;
      int gn = n0 + wn * 64 + j * 16 + l15;
#pragma unroll
      for (int r = 0; r < 4; r++) {
        int gm = gmBase + r;
        if (gm >= M) continue;
        float v = acc[i][j][r];
        if (mode == 0) {
          obf[((size_t)(gn >> 5) * M + gm) * 32 + (gn & 31)] = f2bf(v);
        } else if (mode == 1) {
          obf[(size_t)gm * N + gn] = f2bf(v * scale);
        } else if (mode == 2) {
          of32[(size_t)gm * N + gn] += gamma[gn] * (v + bias[gn]);
        } else {
          float x = v + bias[gn];
          obf[(size_t)gm * N + gn] = f2bf(0.5f * x * (1.f + erff(x * 0.70710678118654752f)));
        }
      }
    }
  }
}

// ---------------- MFMA flash attention ----------------
// Block = (b,h): b = bid&63, h = bid>>6. 4 waves; wave w handles token-tiles w, w+4, ... (32 tok).
// kvb planes: K at plane h, V at plane 8+h; plane = [134400 tokens][32] bf16.
// qb: [b*75+q][256] bf16, pre-scaled by 1/sqrt(32)*log2(e).
// Swapped QK^T: S^T_tile = mfma(A=K rows, B=Q cols) -> lane holds 8 P values for one q.
__global__ __launch_bounds__(256) void k_attn(const u16* __restrict__ qb,
                                              const u16* __restrict__ kvb,
                                              u16* __restrict__ obf) {
  __shared__ u16 VtS[4][32][36];     // padded V tile per wave
  __shared__ uint32_t Pbuf[4][16][20];  // P row-major [q][t], 80B rows (16B aligned)
  __shared__ float maccS[4][2560];   // per-wave partial O (80 rows x 32 d)
  __shared__ float mlS[4][160];      // per-wave m[80], l[80]

  const int bid = blockIdx.x;
  const int b = bid & 63, h = bid >> 6;
  const int tid = threadIdx.x, lane = tid & 63, w = tid >> 6;
  const int l15 = lane & 15, g = lane >> 4;

  const u16* Kp = kvb + ((size_t)h * 134400 + (size_t)b * 2100) * 32;
  const u16* Vp = kvb + ((size_t)(8 + h) * 134400 + (size_t)b * 2100) * 32;

  // Q fragments (B operand: col=q=l15, k=d=g*8+e), resident all kernel
  bf16x8 bq[5];
#pragma unroll
  for (int qt = 0; qt < 5; qt++) {
    int q = qt * 16 + l15; if (q > 74) q = 74;
    s16x8 qv = *(const s16x8*)(qb + (size_t)(b * 75 + q) * 256 + h * 32 + g * 8);
    bq[qt] = __builtin_bit_cast(bf16x8, qv);
  }

  f32x4 acc[5][2] = {};
  float mlc[5], llc[5];
#pragma unroll
  for (int qt = 0; qt < 5; qt++) { mlc[qt] = -1e30f; llc[qt] = 0.f; }

  // prefetch tile w
  s16x8 kfA, kfB, vvA, vvB;
  {
    int t0 = w * 32;
    int ta = t0 + l15; if (ta > 2099) ta = 2099;
    int tb = t0 + 16 + l15; if (tb > 2099) tb = 2099;
    kfA = *(const s16x8*)(Kp + (size_t)ta * 32 + g * 8);
    kfB = *(const s16x8*)(Kp + (size_t)tb * 32 + g * 8);
    int tga = t0 + (lane >> 2); if (tga > 2099) tga = 2099;
    int tgb = t0 + ((lane + 64) >> 2); if (tgb > 2099) tgb = 2099;
    vvA = *(const s16x8*)(Vp + (size_t)tga * 32 + (lane & 3) * 8);
    vvB = *(const s16x8*)(Vp + (size_t)tgb * 32 + (lane & 3) * 8);
  }

  for (int tt = w; tt < 66; tt += 4) {
    const int t0 = tt * 32;
    // stage V tile to LDS (padded rows)
    {
      u16* d0 = &VtS[w][lane >> 2][(lane & 3) * 8];
      u16* d1 = &VtS[w][(lane + 64) >> 2][(lane & 3) * 8];
#pragma unroll
      for (int e = 0; e < 8; e++) d0[e] = (u16)vvA[e];
#pragma unroll
      for (int e = 0; e < 8; e++) d1[e] = (u16)vvB[e];
    }
    bf16x8 bA = __builtin_bit_cast(bf16x8, kfA);
    bf16x8 bB = __builtin_bit_cast(bf16x8, kfB);
    // V fragments (B operand: col=d, k=t): scalar LDS reads, ~2-way banked
    s16x8 v0, v1;
#pragma unroll
    for (int e = 0; e < 8; e++) {
      v0[e] = (short)VtS[w][8 * g + e][l15];
      v1[e] = (short)VtS[w][8 * g + e][16 + l15];
    }
    bf16x8 bv0 = __builtin_bit_cast(bf16x8, v0);
    bf16x8 bv1 = __builtin_bit_cast(bf16x8, v1);
    // prefetch next tile's globals (hidden under compute)
    int tn = tt + 4;
    if (tn < 66) {
      int t0n = tn * 32;
      int ta = t0n + l15; if (ta > 2099) ta = 2099;
      int tb = t0n + 16 + l15; if (tb > 2099) tb = 2099;
      kfA = *(const s16x8*)(Kp + (size_t)ta * 32 + g * 8);
      kfB = *(const s16x8*)(Kp + (size_t)tb * 32 + g * 8);
      int tga = t0n + (lane >> 2); if (tga > 2099) tga = 2099;
      int tgb = t0n + ((lane + 64) >> 2); if (tgb > 2099) tgb = 2099;
      vvA = *(const s16x8*)(Vp + (size_t)tga * 32 + (lane & 3) * 8);
      vvB = *(const s16x8*)(Vp + (size_t)tgb * 32 + (lane & 3) * 8);
    }
    const bool lastTile = (t0 == 2080);

#pragma unroll
    for (int qt = 0; qt < 5; qt++) {
      f32x4 z = {0.f, 0.f, 0.f, 0.f};
      f32x4 sA = mfma16(bA, bq[qt], z);   // rows t0+0..15
      f32x4 sB = mfma16(bB, bq[qt], z);   // rows t0+16..31
      if (lastTile && g >= 1) {           // tokens t0+16+4g+r >= 2100
        sB[0] = sB[1] = sB[2] = sB[3] = -1e30f;
      }
      float px = fmaxf(fmaxf(fmaxf(sA[0], sA[1]), fmaxf(sA[2], sA[3])),
                       fmaxf(fmaxf(sB[0], sB[1]), fmaxf(sB[2], sB[3])));
      px = fmaxf(px, __shfl_xor(px, 16, 64));
      px = fmaxf(px, __shfl_xor(px, 32, 64));
      float mq = mlc[qt];
      if (!__all(px <= mq + 8.f)) {       // defer-max (T13)
        float mn = fmaxf(mq, px);
        float rs = exp2f(mq - mn);
        mlc[qt] = mn;
        llc[qt] *= rs;
#pragma unroll
        for (int r = 0; r < 4; r++) {
          float rr = __shfl(rs, ((lane >> 4) << 2) + r, 64);
          acc[qt][0][r] *= rr;
          acc[qt][1][r] *= rr;
        }
        mq = mn;
      }
      f32x4 pA, pB;
#pragma unroll
      for (int r = 0; r < 4; r++) {
        pA[r] = exp2f(sA[r] - mq);
        pB[r] = exp2f(sB[r] - mq);
      }
      float ps = pA[0] + pA[1] + pA[2] + pA[3] + pB[0] + pB[1] + pB[2] + pB[3];
      ps += __shfl_xor(ps, 16, 64);
      ps += __shfl_xor(ps, 32, 64);
      llc[qt] += ps;
      // pack P -> LDS [q][t] (lane's q = l15, t = 4g+r / 16+4g+r)
      uint32_t* Pu = &Pbuf[w][l15][0];
      Pu[2 * g]     = pkbf(pA[0], pA[1]);
      Pu[2 * g + 1] = pkbf(pA[2], pA[3]);
      Pu[8 + 2 * g]     = pkbf(pB[0], pB[1]);
      Pu[8 + 2 * g + 1] = pkbf(pB[2], pB[3]);
      // read P A-fragment (row=q=l15, k=t=8g..8g+7)
      uint4 pu = *(const uint4*)&Pbuf[w][l15][4 * g];
      bf16x8 bp = __builtin_bit_cast(bf16x8, pu);
      acc[qt][0] = mfma16(bp, bv0, acc[qt][0]);
      acc[qt][1] = mfma16(bp, bv1, acc[qt][1]);
    }
  }

  // dump per-wave partials
#pragma unroll
  for (int qt = 0; qt < 5; qt++)
#pragma unroll
    for (int dh = 0; dh < 2; dh++)
#pragma unroll
      for (int r = 0; r < 4; r++) {
        int q = qt * 16 + 4 * g + r;
        maccS[w][q * 32 + dh * 16 + l15] = acc[qt][dh][r];
      }
  if (lane < 16) {
#pragma unroll
    for (int qt = 0; qt < 5; qt++) {
      mlS[w][qt * 16 + l15] = mlc[qt];
      mlS[w][80 + qt * 16 + l15] = llc[qt];
    }
  }
  __syncthreads();

  // combine 4 wave-partials, write out
  for (int idx = tid; idx < 2400; idx += 256) {
    int q = idx >> 5, d = idx & 31;
    float M = -1e30f;
#pragma unroll
    for (int ww = 0; ww < 4; ww++) M = fmaxf(M, mlS[ww][q]);
    float L = 0.f, O = 0.f;
#pragma unroll
    for (int ww = 0; ww < 4; ww++) {
      float sc = exp2f(mlS[ww][q] - M);
      L += mlS[ww][80 + q] * sc;
      O += maccS[ww][q * 32 + d] * sc;
    }
    obf[(size_t)(b * 75 + q) * 256 + h * 32 + d] = f2bf(O / L);
  }
}

// ---------------- host ----------------
extern "C" void kernel_launch(void* const* d_in, const int* in_sizes, int n_in,
                              void* d_out, int out_size, void* d_ws, size_t ws_size,
                              hipStream_t stream) {
  const float* x_cls   = (const float*)d_in[0];
  const float* x_patch = (const float*)d_in[1];
  const float* ln1_w   = (const float*)d_in[2];
  const float* ln1_b   = (const float*)d_in[3];
  const float* q_w     = (const float*)d_in[4];
  const float* k_w     = (const float*)d_in[5];
  const float* v_w     = (const float*)d_in[6];
  const float* proj_w  = (const float*)d_in[7];
  const float* proj_b  = (const float*)d_in[8];
  const float* ln2_w   = (const float*)d_in[9];
  const float* ln2_b   = (const float*)d_in[10];
  const float* fc1_w   = (const float*)d_in[11];
  const float* fc1_b   = (const float*)d_in[12];
  const float* fc2_w   = (const float*)d_in[13];
  const float* fc2_b   = (const float*)d_in[14];
  const float* gamma1  = (const float*)d_in[15];
  const float* gamma2  = (const float*)d_in[16];
  float* xc = (float*)d_out;

  char* ws = (char*)d_ws;
  size_t off = 0;
  auto alloc = [&](size_t bytes) {
    char* p = ws + off;
    off += (bytes + 255) & ~(size_t)255;
    return p;
  };
  u16* un    = (u16*)alloc(134400ull * 256 * 2);
  u16* uncls = (u16*)alloc(4800ull * 256 * 2);
  u16* kvb   = (u16*)alloc(134400ull * 512 * 2);
  u16* qb    = (u16*)alloc(4800ull * 256 * 2);
  u16* ob    = (u16*)alloc(4800ull * 256 * 2);
  u16* xn    = (u16*)alloc(4800ull * 256 * 2);
  u16* hb    = (u16*)alloc(4800ull * 1024 * 2);
  u16* qp    = (u16*)alloc(2ull * 65536 * 2);
  u16* kvp   = (u16*)alloc(2ull * 131072 * 2);
  u16* pjp   = (u16*)alloc(2ull * 65536 * 2);
  u16* f1p   = (u16*)alloc(2ull * 262144 * 2);
  u16* f2p   = (u16*)alloc(2ull * 262144 * 2);

  k_copy<<<1200, 256, 0, stream>>>(x_cls, xc, 307200);
  for (int i = 0; i < 2; i++) {
    k_cast4<<<64, 256, 0, stream>>>(q_w + i * 65536, qp + i * 65536, 16384);
    k_cast4<<<64, 256, 0, stream>>>(k_w + i * 65536, kvp + i * 131072, 16384);
    k_cast4<<<64, 256, 0, stream>>>(v_w + i * 65536, kvp + i * 131072 + 65536, 16384);
    k_cast4<<<64, 256, 0, stream>>>(proj_w + i * 65536, pjp + i * 65536, 16384);
    k_cast4<<<256, 256, 0, stream>>>(fc1_w + i * 262144, f1p + i * 262144, 65536);
    k_cast4<<<256, 256, 0, stream>>>(fc2_w + i * 262144, f2p + i * 262144, 65536);
  }

  // 1/sqrt(32) * log2(e)  (softmax done in exp2 domain)
  const float qscale = 0.25503489f;
  for (int i = 0; i < 2; i++) {
    k_ln<<<33600, 256, 0, stream>>>(xc, x_patch, ln1_w + i * 256, ln1_b + i * 256,
                                    un, uncls, 1, 134400);
    dim3 gkv(1050, 4);
    k_gemm<<<gkv, 256, 0, stream>>>(un, kvp + i * 131072, 134400, 512, 256, 0, 0.f,
                                    nullptr, nullptr, kvb, nullptr);
    dim3 gq(38, 2);
    k_gemm<<<gq, 256, 0, stream>>>(uncls, qp + i * 65536, 4800, 256, 256, 1, qscale,
                                   nullptr, nullptr, qb, nullptr);
    k_attn<<<512, 256, 0, stream>>>(qb, kvb, ob);
    k_gemm<<<gq, 256, 0, stream>>>(ob, pjp + i * 65536, 4800, 256, 256, 2, 0.f,
                                   proj_b + i * 256, gamma1 + i * 256, nullptr, xc);
    k_ln<<<1200, 256, 0, stream>>>(xc, nullptr, ln2_w + i * 256, ln2_b + i * 256,
                                   xn, nullptr, 0, 4800);
    dim3 gf1(38, 8);
    k_gemm<<<gf1, 256, 0, stream>>>(xn, f1p + i * 262144, 4800, 1024, 256, 3, 0.f,
                                    fc1_b + i * 1024, nullptr, hb, nullptr);
    k_gemm<<<gq, 256, 0, stream>>>(hb, f2p + i * 262144, 4800, 256, 1024, 2, 0.f,
                                   fc2_b + i * 256, gamma2 + i * 256, nullptr, xc);
  }
}